// Round 15
// baseline (677.682 us; speedup 1.0000x reference)
//
#include <hip/hip_runtime.h>

typedef _Float16 v8hf __attribute__((ext_vector_type(8)));
typedef __fp16   v2fp __attribute__((ext_vector_type(2)));
typedef float    v4f  __attribute__((ext_vector_type(4)));

#define MFMA16(a, b, c) __builtin_amdgcn_mfma_f32_16x16x32_f16((a), (b), (c), 0, 0, 0)

#define TT 512
#define NTH 512     // 8 waves: wid 0-3 = L1 (one/SIMD), wid 4-7 = L2+L3+head partner
#define KS 2.8853900817779268f   // 2*log2(e), folded into weights+biases
#define CL 13.8498724f           // 4.8 * KS

// dynamic LDS, per pipeline p (0..3), 16 batches each:
//   h1 ring: 4 entries x 4 slots x 1024 B @ p*16384          (64 KB)
//   oring:   [16 b][64 t][2] f32          @ 65536 + p*8192   (32 KB)
// nu k-map (A and B share it, HW perm cancels): nu(r,g,e)=32r+16(e>>2)+4g+(e&3)
#define SMEMB 98304
extern __shared__ __align__(16) char SMp[];

// tanh of pre-scaled z (z = KS*preact): 4 exp2 + 1 rcp; clamp |x|<=4.8 (err 1.35e-4).
__device__ __forceinline__ v4f tanh4s(v4f z) {
    float z0 = __builtin_amdgcn_fmed3f(z[0], -CL, CL);
    float z1 = __builtin_amdgcn_fmed3f(z[1], -CL, CL);
    float z2 = __builtin_amdgcn_fmed3f(z[2], -CL, CL);
    float z3 = __builtin_amdgcn_fmed3f(z[3], -CL, CL);
    float a0 = __builtin_amdgcn_exp2f(z0) + 1.f;
    float a1 = __builtin_amdgcn_exp2f(z1) + 1.f;
    float a2 = __builtin_amdgcn_exp2f(z2) + 1.f;
    float a3 = __builtin_amdgcn_exp2f(z3) + 1.f;
    float P = a0 * a1, Q = a2 * a3;
    float R = __builtin_amdgcn_rcpf(P * Q);
    float iP = Q * R, iQ = P * R;
    v4f t;
    t[0] = 1.f - 2.f * (a1 * iP);
    t[1] = 1.f - 2.f * (a0 * iP);
    t[2] = 1.f - 2.f * (a3 * iQ);
    t[3] = 1.f - 2.f * (a2 * iQ);
    return t;
}

__device__ __forceinline__ unsigned pkrtz(float a, float b) {
    union { v2fp h; unsigned u; } x;
    x.h = __builtin_amdgcn_cvt_pkrtz(a, b);
    return x.u;
}
__device__ __forceinline__ v8hf mk8(unsigned a, unsigned b, unsigned c, unsigned d) {
    union { unsigned u[4]; v8hf h; } x;
    x.u[0] = a; x.u[1] = b; x.u[2] = c; x.u[3] = d;
    return x.h;
}

__global__ __launch_bounds__(NTH, 2)
void rnn3_pp(const float* __restrict__ xg,
             const float* __restrict__ Wih1, const float* __restrict__ Whh1,
             const float* __restrict__ bih1, const float* __restrict__ bhh1,
             const float* __restrict__ Wih2, const float* __restrict__ Whh2,
             const float* __restrict__ bih2, const float* __restrict__ bhh2,
             const float* __restrict__ Wih3, const float* __restrict__ Whh3,
             const float* __restrict__ bih3, const float* __restrict__ bhh3,
             const float* __restrict__ Wo1,  const float* __restrict__ bo1,
             const float* __restrict__ Wo2,  const float* __restrict__ bo2,
             float* __restrict__ outg)
{
    const int tid   = threadIdx.x;
    const int lane  = tid & 63;
    const int wid   = tid >> 6;
    const int col   = lane & 15;   // batch index within pipeline
    const int g     = lane >> 4;
    const int p     = wid & 3;     // pipeline
    const int bbase = blockIdx.x * 64 + p * 16;
    const unsigned l16 = (unsigned)lane * 16u;
    const v4f z4 = {0.f, 0.f, 0.f, 0.f};
    const v8hf z8 = (v8hf)(_Float16)0.f;

    auto ldA = [&](const float* W, int rows, int cols, int jg, int kt) -> v8hf {
        v8hf r;
        #pragma unroll
        for (int e = 0; e < 8; ++e) {
            const int kl = 32 * kt + 16 * (e >> 2) + 4 * g + (e & 3);
            float v = (jg < rows && kl < cols) ? W[jg * cols + kl] * KS : 0.f;
            r[e] = (_Float16)v;
        }
        return r;
    };
    auto ldA1 = [&](int jg, int kt) -> v8hf {   // Whh1 + x weights at logical k=112,113
        v8hf r;
        #pragma unroll
        for (int e = 0; e < 8; ++e) {
            const int kl = 32 * kt + 16 * (e >> 2) + 4 * g + (e & 3);
            float v = 0.f;
            if (jg < 100) {
                if (kl < 100)       v = Whh1[jg * 100 + kl];
                else if (kl == 112) v = Wih1[jg * 2];
                else if (kl == 113) v = Wih1[jg * 2 + 1];
            }
            r[e] = (_Float16)(v * KS);
        }
        return r;
    };
    auto mkbias = [&](const float* bi, const float* bh, int n, int t) -> v4f {
        v4f b;
        #pragma unroll
        for (int i = 0; i < 4; ++i) {
            const int j = 16 * t + 4 * g + i;
            b[i] = (j < n) ? KS * (bi[j] + bh[j]) : 0.f;
        }
        return b;
    };

    if (wid < 4) {
        // ================= L1 wave: full layer-1 recurrence in registers =================
        v8hf W1[7][4]; v4f B1[7];
        #pragma unroll
        for (int t = 0; t < 7; ++t) {
            #pragma unroll
            for (int kt = 0; kt < 4; ++kt) W1[t][kt] = ldA1(16 * t + col, kt);
            B1[t] = mkbias(bih1, bhh1, 100, t);
        }
        const float* xrow = xg + (size_t)(bbase + col) * (TT * 2);
        v8hf S0 = z8, S1 = z8, S2 = z8, S3;
        {
            float2 x0 = *(const float2*)(xrow);
            S3 = mk8(0u, 0u, (g == 0) ? pkrtz(x0.x, x0.y) : 0u, 0u);
        }
        float2 xn = *(const float2*)(xrow + 2);   // x(1)
        const unsigned wbase = (unsigned)p * 16384u;
        __builtin_amdgcn_s_setprio(1);
        for (int k = 0; k < 257; ++k) {
            #pragma unroll
            for (int sub = 0; sub < 2; ++sub) {
                const int s = 2 * k + sub;
                if (s < TT) {
                    unsigned xu = (g == 0) ? pkrtz(xn.x, xn.y) : 0u;
                    const int sn = (s + 2 < TT) ? s + 2 : TT - 1;
                    xn = *(const float2*)(xrow + 2 * sn);
                    unsigned lo[7], hi[7];
                    #pragma unroll
                    for (int t = 0; t < 7; ++t) {
                        v4f pa = B1[t], qa = z4;
                        pa = MFMA16(W1[t][0], S0, pa); qa = MFMA16(W1[t][1], S1, qa);
                        pa = MFMA16(W1[t][2], S2, pa); qa = MFMA16(W1[t][3], S3, qa);
                        v4f r = tanh4s(pa + qa);
                        lo[t] = pkrtz(r[0], r[1]); hi[t] = pkrtz(r[2], r[3]);
                    }
                    S0 = mk8(lo[0], hi[0], lo[1], hi[1]);
                    S1 = mk8(lo[2], hi[2], lo[3], hi[3]);
                    S2 = mk8(lo[4], hi[4], lo[5], hi[5]);
                    S3 = mk8(lo[6], hi[6], xu, 0u);
                    char* wb = SMp + wbase + (unsigned)(s & 3) * 4096u + l16;
                    *(v8hf*)(wb)        = S0;
                    *(v8hf*)(wb + 1024) = S1;
                    *(v8hf*)(wb + 2048) = S2;
                    *(v8hf*)(wb + 3072) = S3;
                }
            }
            __syncthreads();
        }
    } else {
        // ============ consumer wave: L2 + L3 + head, all states in registers ============
        v8hf Wi2[4][4], Wh2[4][2], Wi3[2][2], Wh3[2], We;
        v4f B2[4], B3[2], BH;
        #pragma unroll
        for (int t = 0; t < 4; ++t) {
            #pragma unroll
            for (int kt = 0; kt < 4; ++kt) Wi2[t][kt] = ldA(Wih2, 60, 100, 16 * t + col, kt);
            Wh2[t][0] = ldA(Whh2, 60, 60, 16 * t + col, 0);
            Wh2[t][1] = ldA(Whh2, 60, 60, 16 * t + col, 1);
            B2[t] = mkbias(bih2, bhh2, 60, t);
        }
        #pragma unroll
        for (int t = 0; t < 2; ++t) {
            Wi3[t][0] = ldA(Wih3, 30, 60, 16 * t + col, 0);
            Wi3[t][1] = ldA(Wih3, 30, 60, 16 * t + col, 1);
            Wh3[t]    = ldA(Whh3, 30, 30, 16 * t + col, 0);
            B3[t] = mkbias(bih3, bhh3, 30, t);
        }
        #pragma unroll
        for (int e = 0; e < 8; ++e) {   // W_eff = Wo2 @ Wo1 (2 x 30), UNscaled
            const int kl = 16 * (e >> 2) + 4 * g + (e & 3);
            float v = 0.f;
            if (col < 2 && kl < 30) {
                #pragma unroll
                for (int u = 0; u < 10; ++u) v += Wo2[col * 10 + u] * Wo1[u * 30 + kl];
            }
            We[e] = (_Float16)v;
        }
        #pragma unroll
        for (int i = 0; i < 4; ++i) {
            float bv = 0.f;
            if (g == 0 && i < 2) {
                bv = bo2[i];
                #pragma unroll
                for (int u = 0; u < 10; ++u) bv += Wo2[i * 10 + u] * bo1[u];
            }
            BH[i] = bv;
        }
        v8hf T0 = z8, T1 = z8, S3r = z8;
        const unsigned rbase = (unsigned)p * 16384u;
        const unsigned obase = 65536u + (unsigned)p * 8192u;
        for (int k = 0; k < 257; ++k) {
            #pragma unroll
            for (int sub = 0; sub < 2; ++sub) {
                const int t = 2 * k + sub - 2;
                if (t >= 0 && t < TT) {
                    const char* rb = SMp + rbase + (unsigned)(t & 3) * 4096u + l16;
                    v8hf G0 = *(const v8hf*)(rb);
                    v8hf G1 = *(const v8hf*)(rb + 1024);
                    v8hf G2 = *(const v8hf*)(rb + 2048);
                    v8hf G3 = *(const v8hf*)(rb + 3072);
                    unsigned lo[4], hi[4];
                    #pragma unroll
                    for (int tt = 0; tt < 4; ++tt) {
                        v4f pa = B2[tt], qa = z4, ra = z4;
                        pa = MFMA16(Wi2[tt][0], G0, pa);
                        qa = MFMA16(Wi2[tt][1], G1, qa);
                        ra = MFMA16(Wh2[tt][0], T0, ra);
                        pa = MFMA16(Wi2[tt][2], G2, pa);
                        qa = MFMA16(Wi2[tt][3], G3, qa);
                        ra = MFMA16(Wh2[tt][1], T1, ra);
                        v4f r = tanh4s(pa + qa + ra);
                        lo[tt] = pkrtz(r[0], r[1]); hi[tt] = pkrtz(r[2], r[3]);
                    }
                    T0 = mk8(lo[0], hi[0], lo[1], hi[1]);
                    T1 = mk8(lo[2], hi[2], lo[3], hi[3]);
                    unsigned lo3[2], hi3[2];
                    #pragma unroll
                    for (int tt = 0; tt < 2; ++tt) {
                        v4f pa = B3[tt], qa = z4;
                        pa = MFMA16(Wi3[tt][0], T0, pa);
                        qa = MFMA16(Wi3[tt][1], T1, qa);
                        pa = MFMA16(Wh3[tt], S3r, pa);
                        v4f r = tanh4s(pa + qa);
                        lo3[tt] = pkrtz(r[0], r[1]); hi3[tt] = pkrtz(r[2], r[3]);
                    }
                    S3r = mk8(lo3[0], hi3[0], lo3[1], hi3[1]);
                    v4f o = BH;
                    o = MFMA16(We, S3r, o);
                    if (g == 0)
                        *(float2*)(SMp + obase + (unsigned)col * 512u + ((unsigned)t & 63u) * 8u)
                            = make_float2(o[0], o[1]);
                }
            }
            if (k >= 16 && (k & 15) == 0) {     // flush own oring block [2k-32, 2k-1]
                const int tb = 2 * k - 32;
                const unsigned rbo = obase + (((unsigned)tb & 63u) >> 1) * 16u;
                #pragma unroll
                for (int jj = 0; jj < 4; ++jj) {
                    const int f = lane + 64 * jj;
                    const int b = f >> 4, kk = f & 15;
                    float4 v = *(const float4*)(SMp + rbo + (unsigned)b * 512u + (unsigned)kk * 16u);
                    *(float4*)(outg + ((size_t)(bbase + b) * TT + tb) * 2 + 4 * kk) = v;
                }
            }
            __syncthreads();
        }
    }
}

extern "C" void kernel_launch(void* const* d_in, const int* in_sizes, int n_in,
                              void* d_out, int out_size, void* d_ws, size_t ws_size,
                              hipStream_t stream) {
    (void)in_sizes; (void)n_in; (void)d_ws; (void)ws_size; (void)out_size;
    const float* x     = (const float*)d_in[0];
    const float* W_ih1 = (const float*)d_in[1];
    const float* W_hh1 = (const float*)d_in[2];
    const float* b_ih1 = (const float*)d_in[3];
    const float* b_hh1 = (const float*)d_in[4];
    const float* W_ih2 = (const float*)d_in[5];
    const float* W_hh2 = (const float*)d_in[6];
    const float* b_ih2 = (const float*)d_in[7];
    const float* b_hh2 = (const float*)d_in[8];
    const float* W_ih3 = (const float*)d_in[9];
    const float* W_hh3 = (const float*)d_in[10];
    const float* b_ih3 = (const float*)d_in[11];
    const float* b_hh3 = (const float*)d_in[12];
    const float* W_o1  = (const float*)d_in[13];
    const float* b_o1  = (const float*)d_in[14];
    const float* W_o2  = (const float*)d_in[15];
    const float* b_o2  = (const float*)d_in[16];
    float* out = (float*)d_out;

    hipFuncSetAttribute((const void*)rnn3_pp,
                        hipFuncAttributeMaxDynamicSharedMemorySize, SMEMB);
    rnn3_pp<<<2048 / 64, NTH, SMEMB, stream>>>(
        x, W_ih1, W_hh1, b_ih1, b_hh1,
        W_ih2, W_hh2, b_ih2, b_hh2,
        W_ih3, W_hh3, b_ih3, b_hh3,
        W_o1, b_o1, W_o2, b_o2, out);
}

// Round 16
// 331.194 us; speedup vs baseline: 2.0462x; 2.0462x over previous
//
#include <hip/hip_runtime.h>

typedef _Float16 v8hf __attribute__((ext_vector_type(8)));
typedef float    v4f  __attribute__((ext_vector_type(4)));

#define MFMA16(a, b, c) __builtin_amdgcn_mfma_f32_16x16x32_f16((a), (b), (c), 0, 0, 0)

#define TT 512
#define BT 16       // batch rows (= MFMA N)
#define NTH 1024    // 16 thin waves, 4/SIMD; sync = LDS flags, NO in-loop barriers
#define KS 2.8853900817779268f   // 2*log2(e), folded into weights+biases
#define CL 13.8498724f           // 4.8 * KS

// Dynamic LDS (bytes). nu k-map (A and B share it -> HW perm cancels):
//   nu(r,g,e) = 32r + 16(e>>2) + 4g + (e&3)
//   h1 ring: 8 entries x 4096 @ 0      (4 slots; k: 0..99 h1, 100..111 fake, 112..113 x)
//   h2 ring: 8 entries x 2048 @ 32768
//   h3 ring: 8 entries x 1024 @ 49152
//   oring:   [16 b][64][2] f32 @ 57344
//   xst:     513 x 64          @ 65536  (u32 f16-pair per (t,b))
//   flags:   8 ints            @ 98368
#define H1R 0u
#define H2R 32768u
#define H3R 49152u
#define ORG 57344u
#define XST 65536u
#define FLG 98368u
#define SMEMB 98432

extern __shared__ __align__(16) char SMp[];

#define F_C1 0
#define F_R1 1
#define F_C2 2
#define F_R2 3
#define F_C3 4
#define F_R3 5
#define F_CO 6
#define F_FO 7

__device__ __forceinline__ int* flagp(int i) { return (int*)(SMp + FLG) + i; }
__device__ __forceinline__ void waitge(int i, int tgt) {
    int* f = flagp(i);
    while (__hip_atomic_load(f, __ATOMIC_ACQUIRE, __HIP_MEMORY_SCOPE_WORKGROUP) < tgt)
        __builtin_amdgcn_s_sleep(1);
}
__device__ __forceinline__ void bump(int i, int v, int lane) {
    if (lane == 0)
        __hip_atomic_fetch_add(flagp(i), v, __ATOMIC_RELEASE, __HIP_MEMORY_SCOPE_WORKGROUP);
}

// tanh of pre-scaled z (z = KS*preact): 4 exp2 + 1 rcp; clamp |x|<=4.8 (err 1.35e-4).
__device__ __forceinline__ v4f tanh4s(v4f z) {
    float z0 = __builtin_amdgcn_fmed3f(z[0], -CL, CL);
    float z1 = __builtin_amdgcn_fmed3f(z[1], -CL, CL);
    float z2 = __builtin_amdgcn_fmed3f(z[2], -CL, CL);
    float z3 = __builtin_amdgcn_fmed3f(z[3], -CL, CL);
    float a0 = __builtin_amdgcn_exp2f(z0) + 1.f;
    float a1 = __builtin_amdgcn_exp2f(z1) + 1.f;
    float a2 = __builtin_amdgcn_exp2f(z2) + 1.f;
    float a3 = __builtin_amdgcn_exp2f(z3) + 1.f;
    float P = a0 * a1, Q = a2 * a3;
    float R = __builtin_amdgcn_rcpf(P * Q);
    float iP = Q * R, iQ = P * R;
    v4f t;
    t[0] = 1.f - 2.f * (a1 * iP);
    t[1] = 1.f - 2.f * (a0 * iP);
    t[2] = 1.f - 2.f * (a3 * iQ);
    t[3] = 1.f - 2.f * (a2 * iQ);
    return t;
}

__device__ __forceinline__ unsigned pk2h(float a, float b) {
    union { _Float16 h[2]; unsigned u; } x;
    x.h[0] = (_Float16)a; x.h[1] = (_Float16)b;
    return x.u;
}

__global__ __launch_bounds__(NTH, 1)
void rnn3_pc(const float* __restrict__ xg,
             const float* __restrict__ Wih1, const float* __restrict__ Whh1,
             const float* __restrict__ bih1, const float* __restrict__ bhh1,
             const float* __restrict__ Wih2, const float* __restrict__ Whh2,
             const float* __restrict__ bih2, const float* __restrict__ bhh2,
             const float* __restrict__ Wih3, const float* __restrict__ Whh3,
             const float* __restrict__ bih3, const float* __restrict__ bhh3,
             const float* __restrict__ Wo1,  const float* __restrict__ bo1,
             const float* __restrict__ Wo2,  const float* __restrict__ bo2,
             float* __restrict__ outg)
{
    const int tid   = threadIdx.x;
    const int lane  = tid & 63;
    const int wid   = tid >> 6;    // 16 waves; SIMD = wid&3
    const int col   = lane & 15;   // batch index in B/C frags
    const int g     = lane >> 4;   // k-group / C row-group
    const int bbase = blockIdx.x * BT;
    const unsigned l16 = (unsigned)lane * 16u;
    const v4f z4 = {0.f, 0.f, 0.f, 0.f};

    // ---- init: flags, step-(-1) ring entries, xst ----
    if (tid < 8) *flagp(tid) = 0;
    for (int i = tid; i < 1024; i += NTH) ((float*)(SMp + H1R + 7u * 4096u))[i] = 0.f;
    for (int i = tid; i < 512;  i += NTH) ((float*)(SMp + H2R + 7u * 2048u))[i] = 0.f;
    for (int i = tid; i < 256;  i += NTH) ((float*)(SMp + H3R + 7u * 1024u))[i] = 0.f;
    for (int i = tid; i < BT * TT; i += NTH) {
        const int b = i >> 9, t = i & 511;
        float2 xv = *(const float2*)(xg + (size_t)(bbase + b) * (TT * 2) + 2 * t);
        *(unsigned*)(SMp + XST + (unsigned)t * 64u + (unsigned)b * 4u) = pk2h(xv.x, xv.y);
    }
    if (tid < 16) *(unsigned*)(SMp + XST + 512u * 64u + (unsigned)tid * 4u) = 0u;
    __syncthreads();
    if (tid < 16)   // x(0) into entry 7 (step -1), slot3 hi, g==0 lanes
        *(unsigned*)(SMp + H1R + 7u * 4096u + 3072u + (unsigned)tid * 16u + 8u) =
            *(const unsigned*)(SMp + XST + (unsigned)tid * 4u);
    __syncthreads();

    auto ldA = [&](const float* W, int rows, int cols, int jg, int kt) -> v8hf {
        v8hf r;
        #pragma unroll
        for (int e = 0; e < 8; ++e) {
            const int kl = 32 * kt + 16 * (e >> 2) + 4 * g + (e & 3);
            float v = (jg < rows && kl < cols) ? W[jg * cols + kl] * KS : 0.f;
            r[e] = (_Float16)v;
        }
        return r;
    };
    auto ldA1 = [&](int jg, int kt) -> v8hf {
        v8hf r;
        #pragma unroll
        for (int e = 0; e < 8; ++e) {
            const int kl = 32 * kt + 16 * (e >> 2) + 4 * g + (e & 3);
            float v = 0.f;
            if (jg < 100) {
                if (kl < 100)       v = Whh1[jg * 100 + kl];
                else if (kl == 112) v = Wih1[jg * 2];
                else if (kl == 113) v = Wih1[jg * 2 + 1];
            }
            r[e] = (_Float16)(v * KS);
        }
        return r;
    };
    auto mkbias = [&](const float* bi, const float* bh, int n, int t) -> v4f {
        v4f b;
        #pragma unroll
        for (int i = 0; i < 4; ++i) {
            const int j = 16 * t + 4 * g + i;
            b[i] = (j < n) ? KS * (bi[j] + bh[j]) : 0.f;
        }
        return b;
    };

    if (wid < 7) {
        // ---------- L1 tile wid: consume h1(t-1) [C1>=8t], produce h1(t) ----------
        v8hf WF[4];
        #pragma unroll
        for (int kt = 0; kt < 4; ++kt) WF[kt] = ldA1(16 * wid + col, kt);
        v4f BB0 = mkbias(bih1, bhh1, 100, wid);
        const unsigned woff = H1R + (unsigned)(wid >> 1) * 1024u + (unsigned)(wid & 1) * 8u + l16;
        for (int t = 0; t < TT; ++t) {
            if (t) waitge(F_C1, 8 * t);
            const char* rb = SMp + H1R + (unsigned)((t + 7) & 7) * 4096u + l16;
            v8hf S0 = *(const v8hf*)(rb);
            v8hf S1 = *(const v8hf*)(rb + 1024);
            v8hf S2 = *(const v8hf*)(rb + 2048);
            v8hf S3 = *(const v8hf*)(rb + 3072);
            v4f p = BB0, q = z4;
            p = MFMA16(WF[0], S0, p); q = MFMA16(WF[1], S1, q);
            p = MFMA16(WF[2], S2, p); q = MFMA16(WF[3], S3, q);
            v4f r = tanh4s(p + q);
            uint2 wv; wv.x = pk2h(r[0], r[1]); wv.y = pk2h(r[2], r[3]);
            if (t >= 8) waitge(F_R1, 4 * (t - 7));   // L2 done with h1(t-8)
            *(uint2*)(SMp + woff + (unsigned)(t & 7) * 4096u) = wv;
            bump(F_C1, 1, lane);
        }
    } else if (wid == 7) {
        // ---------- x-stage: write x(t+1) into h1 entry t, slot3 hi ----------
        for (int t = 0; t < TT; ++t) {
            if (t) waitge(F_C1, 8 * t);
            unsigned xv = *(const unsigned*)(SMp + XST + (unsigned)(t + 1) * 64u + (unsigned)col * 4u);
            uint2 wv; wv.x = (g == 0) ? xv : 0u; wv.y = 0u;
            if (t >= 8) waitge(F_R1, 4 * (t - 7));
            *(uint2*)(SMp + H1R + (unsigned)(t & 7) * 4096u + 3072u + l16 + 8u) = wv;
            bump(F_C1, 1, lane);
        }
    } else if (wid < 12) {
        // ---------- L2 tile wid-8: consume h1(t) [C1>=8(t+1)], h2(t-1) [C2>=4t] ----------
        const int t2 = wid - 8;
        const int j = 16 * t2 + col;
        v8hf WF[6];
        #pragma unroll
        for (int kt = 0; kt < 4; ++kt) WF[kt] = ldA(Wih2, 60, 100, j, kt);
        WF[4] = ldA(Whh2, 60, 60, j, 0);
        WF[5] = ldA(Whh2, 60, 60, j, 1);
        v4f BB0 = mkbias(bih2, bhh2, 60, t2);
        const unsigned woff = H2R + (unsigned)(t2 >> 1) * 1024u + (unsigned)(t2 & 1) * 8u + l16;
        for (int t = 0; t < TT; ++t) {
            waitge(F_C1, 8 * (t + 1));
            if (t) waitge(F_C2, 4 * t);
            const char* rb1 = SMp + H1R + (unsigned)(t & 7) * 4096u + l16;
            const char* rb2 = SMp + H2R + (unsigned)((t + 7) & 7) * 2048u + l16;
            v8hf G0 = *(const v8hf*)(rb1);
            v8hf G1 = *(const v8hf*)(rb1 + 1024);
            v8hf G2 = *(const v8hf*)(rb1 + 2048);
            v8hf G3 = *(const v8hf*)(rb1 + 3072);
            v8hf H0 = *(const v8hf*)(rb2);
            v8hf H1 = *(const v8hf*)(rb2 + 1024);
            bump(F_R1, 1, lane);                      // consumed h1(t)
            v4f p = BB0, q = z4, r2 = z4;
            p  = MFMA16(WF[0], G0, p);
            q  = MFMA16(WF[1], G1, q);
            r2 = MFMA16(WF[4], H0, r2);
            p  = MFMA16(WF[2], G2, p);
            q  = MFMA16(WF[3], G3, q);
            r2 = MFMA16(WF[5], H1, r2);
            v4f r = tanh4s(p + q + r2);
            uint2 wv; wv.x = pk2h(r[0], r[1]); wv.y = pk2h(r[2], r[3]);
            if (t >= 8) waitge(F_R2, 2 * (t - 7));    // L3 done with h2(t-8)
            *(uint2*)(SMp + woff + (unsigned)(t & 7) * 2048u) = wv;
            bump(F_C2, 1, lane);
        }
    } else if (wid < 14) {
        // ---------- L3 tile wid-12: consume h2(t) [C2>=4(t+1)], h3(t-1) [C3>=2t] ----------
        const int t3 = wid - 12;
        const int j = 16 * t3 + col;
        v8hf WF[3];
        WF[0] = ldA(Wih3, 30, 60, j, 0);
        WF[1] = ldA(Wih3, 30, 60, j, 1);
        WF[2] = ldA(Whh3, 30, 30, j, 0);
        v4f BB0 = mkbias(bih3, bhh3, 30, t3);
        const unsigned woff = H3R + (unsigned)(t3 & 1) * 8u + l16;
        for (int t = 0; t < TT; ++t) {
            waitge(F_C2, 4 * (t + 1));
            if (t) waitge(F_C3, 2 * t);
            const char* rb2 = SMp + H2R + (unsigned)(t & 7) * 2048u + l16;
            const char* rb3 = SMp + H3R + (unsigned)((t + 7) & 7) * 1024u + l16;
            v8hf G0 = *(const v8hf*)(rb2);
            v8hf G1 = *(const v8hf*)(rb2 + 1024);
            v8hf C0 = *(const v8hf*)(rb3);
            bump(F_R2, 1, lane);                      // consumed h2(t)
            v4f p = BB0, q = z4, r2 = z4;
            p  = MFMA16(WF[0], G0, p);
            q  = MFMA16(WF[1], G1, q);
            r2 = MFMA16(WF[2], C0, r2);
            v4f r = tanh4s(p + q + r2);
            uint2 wv; wv.x = pk2h(r[0], r[1]); wv.y = pk2h(r[2], r[3]);
            if (t >= 8) waitge(F_R3, t - 7);          // head done with h3(t-8)
            *(uint2*)(SMp + woff + (unsigned)(t & 7) * 1024u) = wv;
            bump(F_C3, 1, lane);
        }
    } else if (wid == 14) {
        // ---------- head: consume h3(t) [C3>=2(t+1)], produce o(t) ----------
        v8hf We;
        #pragma unroll
        for (int e = 0; e < 8; ++e) {   // W_eff = Wo2 @ Wo1 (2 x 30), UNscaled
            const int kl = 16 * (e >> 2) + 4 * g + (e & 3);
            float v = 0.f;
            if (col < 2 && kl < 30) {
                #pragma unroll
                for (int u = 0; u < 10; ++u) v += Wo2[col * 10 + u] * Wo1[u * 30 + kl];
            }
            We[e] = (_Float16)v;
        }
        v4f BH;
        #pragma unroll
        for (int i = 0; i < 4; ++i) {
            float bv = 0.f;
            if (g == 0 && i < 2) {
                bv = bo2[i];
                #pragma unroll
                for (int u = 0; u < 10; ++u) bv += Wo2[i * 10 + u] * bo1[u];
            }
            BH[i] = bv;
        }
        for (int t = 0; t < TT; ++t) {
            waitge(F_C3, 2 * (t + 1));
            v8hf C0 = *(const v8hf*)(SMp + H3R + (unsigned)(t & 7) * 1024u + l16);
            bump(F_R3, 1, lane);                      // consumed h3(t)
            v4f o = BH;
            o = MFMA16(We, C0, o);
            if (t >= 64) waitge(F_FO, t - 63);        // oring slot reuse
            if (g == 0)
                *(float2*)(SMp + ORG + (unsigned)col * 512u + ((unsigned)t & 63u) * 8u) =
                    make_float2(o[0], o[1]);
            bump(F_CO, 1, lane);
        }
    } else {
        // ---------- flush: 16 blocks of 32 steps, coalesced float4 ----------
        for (int tb = 0; tb <= 480; tb += 32) {
            waitge(F_CO, tb + 32);
            const unsigned rb = ORG + (((unsigned)tb & 63u) >> 1) * 16u;
            #pragma unroll
            for (int jj = 0; jj < 4; ++jj) {
                const int f = lane + 64 * jj;
                const int b = f >> 4, k = f & 15;
                float4 v = *(const float4*)(SMp + rb + (unsigned)b * 512u + (unsigned)k * 16u);
                *(float4*)(outg + ((size_t)(bbase + b) * TT + tb) * 2 + 4 * k) = v;
            }
            bump(F_FO, 32, lane);
        }
    }
}

extern "C" void kernel_launch(void* const* d_in, const int* in_sizes, int n_in,
                              void* d_out, int out_size, void* d_ws, size_t ws_size,
                              hipStream_t stream) {
    (void)in_sizes; (void)n_in; (void)d_ws; (void)ws_size; (void)out_size;
    const float* x     = (const float*)d_in[0];
    const float* W_ih1 = (const float*)d_in[1];
    const float* W_hh1 = (const float*)d_in[2];
    const float* b_ih1 = (const float*)d_in[3];
    const float* b_hh1 = (const float*)d_in[4];
    const float* W_ih2 = (const float*)d_in[5];
    const float* W_hh2 = (const float*)d_in[6];
    const float* b_ih2 = (const float*)d_in[7];
    const float* b_hh2 = (const float*)d_in[8];
    const float* W_ih3 = (const float*)d_in[9];
    const float* W_hh3 = (const float*)d_in[10];
    const float* b_ih3 = (const float*)d_in[11];
    const float* b_hh3 = (const float*)d_in[12];
    const float* W_o1  = (const float*)d_in[13];
    const float* b_o1  = (const float*)d_in[14];
    const float* W_o2  = (const float*)d_in[15];
    const float* b_o2  = (const float*)d_in[16];
    float* out = (float*)d_out;

    hipFuncSetAttribute((const void*)rnn3_pc,
                        hipFuncAttributeMaxDynamicSharedMemorySize, SMEMB);
    rnn3_pc<<<2048 / BT, NTH, SMEMB, stream>>>(
        x, W_ih1, W_hh1, b_ih1, b_hh1,
        W_ih2, W_hh2, b_ih2, b_hh2,
        W_ih3, W_hh3, b_ih3, b_hh3,
        W_o1, b_o1, W_o2, b_o2, out);
}